// Round 6
// baseline (816.711 us; speedup 1.0000x reference)
//
#include <hip/hip_runtime.h>

// RSSM v6: identical to v5 except rssm_seq persists the GRU weights in
// registers. At 1 block/CU + 2 waves/SIMD, VGPRs are free up to 512/wave:
// __launch_bounds__(512,1) raises the allocator cap (r2's failure was the
// 256-cap + allocator heuristic, not HW). P1's steady-state loop now has
// ZERO weight loads: 27-54 back-to-back register MFMAs per wave.

typedef unsigned short u16;
typedef unsigned int u32;
typedef __attribute__((ext_vector_type(8))) short short8;
typedef __attribute__((ext_vector_type(4))) float f32x4;

#define LL 64
#define OBS_ 200
#define ACT_ 6
#define STO 30
#define OUTC 350

// packed-weight unit offsets (1 unit = 1KB = 64 lanes x 16B)
#define U_WG   0
#define U_PW1  468
#define U_QW1  559
#define U_PW2  741
#define U_QW2  769
#define U_TOT  797
#define QX_OFF (1u << 20)

__device__ __forceinline__ u16 f2b(float f){
  u32 u = __float_as_uint(f);
  u = (u + 0x7fffu + ((u >> 16) & 1u)) >> 16;   // RNE
  return (u16)u;
}
__device__ __forceinline__ float b2f(u16 h){ return __uint_as_float(((u32)h) << 16); }

// stride-512B tiles (h): swizzle byte ^= (r&7)<<4
__device__ __forceinline__ short8 ldA7(const u16* buf, int r, int colStart){
  return *(const short8*)((const char*)buf + r*512 + ((colStart*2) ^ ((r & 7) << 4)));
}
__device__ __forceinline__ void st27(u16* buf, int r, int c, u16 v){
  *(u16*)((char*)buf + r*512 + ((c*2) ^ ((r & 7) << 4))) = v;
}
__device__ __forceinline__ u16 ld27(const u16* buf, int r, int c){
  return *(const u16*)((const char*)buf + r*512 + ((c*2) ^ ((r & 7) << 4)));
}
// stride-448B tiles (sqq/sob/shh/spp): swizzle byte ^= (r&3)<<4
__device__ __forceinline__ short8 ldA3(const u16* buf, int r, int colStart){
  return *(const short8*)((const char*)buf + r*448 + ((colStart*2) ^ ((r & 3) << 4)));
}
__device__ __forceinline__ void st23(u16* buf, int r, int c, u16 v){
  *(u16*)((char*)buf + r*448 + ((c*2) ^ ((r & 3) << 4))) = v;
}
__device__ __forceinline__ void st8_3(u16* buf, int r, int c8, short8 v){
  *(short8*)((char*)buf + r*448 + ((c8*16) ^ ((r & 3) << 4))) = v;
}
__device__ __forceinline__ short8 ldB(const char* wsb, int unit, int lane){
  return *(const short8*)(wsb + (((size_t)unit) << 10) + ((size_t)lane << 4));
}
__device__ __forceinline__ short8 lwq(const u16* sw, int lu, int lane){
  return *(const short8*)((const char*)sw + ((size_t)lu << 10) + (lane << 4));
}
__device__ __forceinline__ f32x4 mfma(short8 a, short8 b, f32x4 c){
  return __builtin_amdgcn_mfma_f32_16x16x32_bf16(a, b, c, 0, 0, 0);
}
__device__ __forceinline__ float sigm(float x){ return 1.f / (1.f + __expf(-x)); }
__device__ __forceinline__ float tanhf_(float x){
  x = fminf(fmaxf(x, -15.f), 15.f);
  float e = __expf(-2.f * x);
  return (1.f - e) / (1.f + e);
}
__device__ __forceinline__ float softplus_(float x){
  return (x > 20.f) ? x : log1pf(__expf(x));
}
__device__ __forceinline__ short8 pack8(f32x4 a, f32x4 b){
  short8 v;
  v[0]=(short)f2b(a[0]); v[1]=(short)f2b(a[1]); v[2]=(short)f2b(a[2]); v[3]=(short)f2b(a[3]);
  v[4]=(short)f2b(b[0]); v[5]=(short)f2b(b[1]); v[6]=(short)f2b(b[2]); v[7]=(short)f2b(b[3]);
  return v;
}

// ---------------- weight packing (UNCHANGED, verified round 1) ---------------
__global__ __launch_bounds__(512) void pack_w(
    const float* W_ih, const float* W_hh, const float* pW1f, const float* qW1f,
    const float* pW2f, const float* qW2f, u16* wsu)
{
  int u = blockIdx.x;
  int t = threadIdx.x;
  int lane = t >> 3, j = t & 7;
  int nl = lane & 15, kg = lane >> 4;
  float v = 0.f;
  if (u < U_PW1) {                       // WG
    int nt = u / 9, ks = u % 9;
    int k = ks*32 + kg*8 + j;
    int c = nt*16 + nl;
    int grow, part, coff;
    if (c < 208)      { grow = c;            part = 0; coff = c; }
    else if (c < 416) { grow = 200 + (c-208); part = 0; coff = c-208; }
    else if (c < 624) { grow = 400 + (c-416); part = 1; coff = c-416; }
    else              { grow = 400 + (c-624); part = 2; coff = c-624; }
    if (coff < 200) {
      if (k < 36)                  { if (part != 2) v = W_ih[grow*36 + k]; }
      else if (k >= 64 && k < 264) { if (part != 1) v = W_hh[grow*200 + (k-64)]; }
    }
  } else if (u < U_QW1) {                // PW1
    int uu = u - U_PW1; int nt = uu / 7, ks = uu % 7;
    int k = ks*32 + kg*8 + j; int n = nt*16 + nl;
    if (n < 200 && k < 200) v = pW1f[n*200 + k];
  } else if (u < U_PW2) {                // QW1
    int uu = u - U_QW1; int nt = uu / 14, ks = uu % 14;
    int k = ks*32 + kg*8 + j; int n = nt*16 + nl;
    if (n < 200) {
      if (k < 200) v = qW1f[n*400 + k];
      else if (k >= 224 && k < 424) v = qW1f[n*400 + 200 + (k-224)];
    }
  } else {                               // PW2 / QW2
    bool isQ = (u >= U_QW2);
    int uu = u - (isQ ? U_QW2 : U_PW2); int nt = uu / 7, ks = uu % 7;
    int k = ks*32 + kg*8 + j; int c = nt*16 + nl;
    int row = (c < 32) ? c : 30 + (c - 32);
    bool ok = (c < 32) ? (c < 30) : ((c - 32) < 30);
    const float* W = isQ ? qW2f : pW2f;
    if (ok && k < 200) v = W[row*200 + k];
  }
  wsu[((size_t)u << 9) + lane*8 + j] = f2b(v);
}

// ---------------- qx kernel (UNCHANGED, verified round 4) --------------------
__global__ __launch_bounds__(512) void qx_k(
    const float* __restrict__ obs, const float* __restrict__ qb1,
    const char* __restrict__ wsb, u16* __restrict__ qxp)
{
  const int tid = threadIdx.x, w = tid >> 6, lane = tid & 63;
  const int nl = lane & 15, kg = lane >> 4;
  const int r0 = blockIdx.x * 16;
  __shared__ __align__(16) u16 sob[16*224];
  for (int i = tid; i < 16*224; i += 512) sob[i] = 0;
  __syncthreads();
  if (tid < 400) {
    int m = tid / 25, c8 = tid % 25;
    const float* op = obs + (size_t)(r0+m)*OBS_ + c8*8;
    f32x4 a = *(const f32x4*)op, b = *(const f32x4*)(op + 4);
    st8_3(sob, m, c8, pack8(a, b));
  }
  __syncthreads();
#pragma unroll
  for (int qi = 0; qi < 2; ++qi) {
    int tq = w + qi*8;
    if (tq < 13) {
      f32x4 acc{0,0,0,0};
#pragma unroll
      for (int ks = 0; ks < 7; ++ks)
        acc = mfma(ldA3(sob, nl, ks*32 + kg*8), ldB(wsb, U_QW1 + tq*14 + ks, lane), acc);
      int n = tq*16 + nl;
      if (n < 200) {
        float b = qb1[n];
#pragma unroll
        for (int i = 0; i < 4; ++i)
          qxp[(size_t)(r0 + kg*4 + i)*OBS_ + n] = f2b(acc[i] + b);
      }
    }
  }
}

// ---------------- prior kernel (UNCHANGED, verified round 4) -----------------
__global__ __launch_bounds__(512) void prior_k(
    const float* __restrict__ pb1, const float* __restrict__ pb2,
    const char* __restrict__ wsb, float* __restrict__ out)
{
  const int tid = threadIdx.x, w = tid >> 6, lane = tid & 63;
  const int nl = lane & 15, kg = lane >> 4;
  const int r0 = blockIdx.x * 16;
  __shared__ __align__(16) u16 shh[16*224];
  __shared__ __align__(16) u16 spp[16*224];
  for (int i = tid; i < 16*224; i += 512) { shh[i] = 0; spp[i] = 0; }
  __syncthreads();
  if (tid < 400) {
    int m = tid / 25, c8 = tid % 25;
    const float* hp = out + (size_t)(r0+m)*OUTC + 150 + c8*8;
    f32x4 a, b;
#pragma unroll
    for (int i = 0; i < 4; ++i) { a[i] = hp[i]; b[i] = hp[4+i]; }
    st8_3(shh, m, c8, pack8(a, b));
  }
  __syncthreads();
#pragma unroll
  for (int qi = 0; qi < 2; ++qi) {
    int tq = w + qi*8;
    if (tq < 13) {
      f32x4 acc{0,0,0,0};
#pragma unroll
      for (int ks = 0; ks < 7; ++ks)
        acc = mfma(ldA3(shh, nl, ks*32 + kg*8), ldB(wsb, U_PW1 + tq*7 + ks, lane), acc);
      int n = tq*16 + nl;
      if (n < 200) {
        float b = pb1[n];
#pragma unroll
        for (int i = 0; i < 4; ++i) {
          float v = acc[i] + b;
          st23(spp, kg*4 + i, n, f2b(v > 0.f ? v : 0.f));
        }
      }
    }
  }
  __syncthreads();
  if (w < 2) {
    f32x4 a0{0,0,0,0}, a1{0,0,0,0};
#pragma unroll
    for (int ks = 0; ks < 7; ++ks) {
      short8 af = ldA3(spp, nl, ks*32 + kg*8);
      a0 = mfma(af, ldB(wsb, U_PW2 + w*7 + ks,     lane), a0);
      a1 = mfma(af, ldB(wsb, U_PW2 + (w+2)*7 + ks, lane), a1);
    }
    int c3 = w*16 + nl;
    if (c3 < 30) {
      float bmu = pb2[c3], bpre = pb2[30 + c3];
#pragma unroll
      for (int i = 0; i < 4; ++i) {
        size_t ob = (size_t)(r0 + kg*4 + i)*OUTC;
        out[ob + c3] = a0[i] + bmu;
        float sp = softplus_(a1[i] + bpre) + 1e-5f;
        out[ob + 30 + c3] = fmaxf(sp, 1e-4f);
      }
    }
  }
}

// ---------------- sequential scan v6: register-persistent GRU weights --------
__global__ __launch_bounds__(512, 1) void rssm_seq(
    const float* __restrict__ act, const float* __restrict__ noise,
    const float* __restrict__ b_ih, const float* __restrict__ b_hh,
    const float* __restrict__ qb2,
    const u16* __restrict__ qxp, const char* __restrict__ wsb,
    float* __restrict__ out)
{
  const int tid  = threadIdx.x;
  const int w    = tid >> 6;      // wave 0..7
  const int lane = tid & 63;
  const int nl   = lane & 15;
  const int kg   = lane >> 4;
  const int m0   = blockIdx.x * 16;

  // LDS weight cache: 119 units = QW1h (tq*7+ks, 91) then QW2 (nt*7+ks, 28)
  __shared__ __align__(16) u16 swq[119*512];
  // h0/h1: [16][256] stride 512B: h 0..199 | s 200..229 | a 230..235 | zeros
  __shared__ __align__(16) u16 h0 [16*256];
  __shared__ __align__(16) u16 h1 [16*256];
  __shared__ __align__(16) u16 sqq[16*224];   // stride 448B

  for (int i = tid; i < 16*256; i += 512) { h0[i]=0; h1[i]=0; }
  for (int i = tid; i < 16*224; i += 512) sqq[i]=0;
  // load LDS weight cache (one-time, 119KB)
  for (int c = tid; c < 119*64; c += 512) {
    int lu = c >> 6, l16 = c & 63;
    int gu = (lu < 91) ? (U_QW1 + (lu/7)*14 + 7 + (lu%7)) : (U_QW2 + (lu - 91));
    *(short8*)((char*)swq + (size_t)c*16) =
        *(const short8*)(wsb + ((size_t)gu << 10) + (l16 << 4));
  }

  // ---- roles ----
  // P1/P2 job1: tq = w (all 8 waves). job2 (waves 3..7): tq2 = w+5 (8..12).
  const int  cj  = w*16 + nl;                       // < 128, always valid
  const bool j2  = (w >= 3);
  const int  tq2 = w + 5;
  const int  cj2 = tq2*16 + nl;
  const bool cj2v = j2 && (cj2 < 200);
  const float bR1 = b_ih[cj]       + b_hh[cj];
  const float bZ1 = b_ih[200 + cj] + b_hh[200 + cj];
  const float bI1 = b_ih[400 + cj];
  const float bH1 = b_hh[400 + cj];
  float bR2=0,bZ2=0,bI2=0,bH2=0;
  if (cj2v) {
    bR2 = b_ih[cj2] + b_hh[cj2];
    bZ2 = b_ih[200+cj2] + b_hh[200+cj2];
    bI2 = b_ih[400+cj2];
    bH2 = b_hh[400+cj2];
  }
  // P3: waves 0,1 (mu tile w, pre tile w+2 of QW2)
  const bool isP3 = (w < 2);
  const int  c3   = w*16 + nl;
  const bool c3v  = isP3 && (c3 < 30);
  float b3mu=0, b3pre=0;
  if (c3v) { b3mu = qb2[c3]; b3pre = qb2[30 + c3]; }
  // act stagers: waves 2,3 (96 lanes)
  const int  t2 = (w - 2)*64 + lane;
  const bool isAct = (w == 2 || w == 3) && (t2 < 96);

  // ---- PERSISTENT GRU weight fragments (registers, loaded once) ----
  // job1 (tq = w): 27 units = 108 VGPRs. job2 (tq2 = w+5): 27 more.
  // For waves 0..2, tq2 = 5..7 (valid units) — loaded but unused; uniform
  // register allocation across waves anyway.
  short8 wR1[9], wZ1[9], wI1[2], wH1[7];
  short8 wR2[9], wZ2[9], wI2[2], wH2[7];
#pragma unroll
  for (int ks = 0; ks < 9; ++ks) {
    wR1[ks] = ldB(wsb, U_WG + w*9 + ks,        lane);
    wR2[ks] = ldB(wsb, U_WG + tq2*9 + ks,      lane);
    wZ1[ks] = ldB(wsb, U_WG + (13+w)*9 + ks,   lane);
    wZ2[ks] = ldB(wsb, U_WG + (13+tq2)*9 + ks, lane);
  }
#pragma unroll
  for (int ks = 0; ks < 2; ++ks) {
    wI1[ks] = ldB(wsb, U_WG + (26+w)*9 + ks,   lane);
    wI2[ks] = ldB(wsb, U_WG + (26+tq2)*9 + ks, lane);
  }
#pragma unroll
  for (int ks = 0; ks < 7; ++ks) {
    wH1[ks] = ldB(wsb, U_WG + (39+w)*9 + 2 + ks,   lane);
    wH2[ks] = ldB(wsb, U_WG + (39+tq2)*9 + 2 + ks, lane);
  }

  __syncthreads();
  // prologue: act(l=0) -> h0 cols 230..235 (s0=h0=0 already)
  if (tid < 96) {
    int m = tid / 6, j = tid % 6;
    st27(h0, m, 230 + j, f2b(act[(size_t)(m0+m)*LL*ACT_ + j]));
  }
  __syncthreads();

#pragma unroll 1
  for (int l = 0; l < LL; ++l) {
    u16* hO = (l & 1) ? h1 : h0;
    u16* hN = (l & 1) ? h0 : h1;
    const size_t outB = (size_t)l*OUTC;

    // ---- step-start prefetches (consumed 1-2 phases later) ----
    float ep[4] = {0,0,0,0};
    if (c3v) {
      const float* np = noise + (size_t)(m0 + kg*4)*LL*STO + (size_t)l*STO + c3;
#pragma unroll
      for (int i = 0; i < 4; ++i) ep[i] = np[(size_t)i*LL*STO];
    }
    float qx1[4], qx2[4] = {0,0,0,0};
#pragma unroll
    for (int i = 0; i < 4; ++i)
      qx1[i] = b2f(qxp[((size_t)(m0 + kg*4 + i)*LL + l)*OBS_ + cj]);
    if (cj2v) {
#pragma unroll
      for (int i = 0; i < 4; ++i)
        qx2[i] = b2f(qxp[((size_t)(m0 + kg*4 + i)*LL + l)*OBS_ + cj2]);
    }
    float av = 0.f;
    if (isAct && (l + 1 < LL))
      av = act[((size_t)(m0 + t2/6)*LL + (l+1))*ACT_ + (t2 % 6)];

    // ================= P1: GRU gates (pure-register MFMA) ===================
    short8 a9[9];
#pragma unroll
    for (int ks = 0; ks < 9; ++ks) {
      const int col = (ks < 2) ? (200 + ks*32 + kg*8) : ((ks-2)*32 + kg*8);
      a9[ks] = ldA7(hO, nl, col);
    }
    if (!j2) {
      f32x4 aR{0,0,0,0}, aZ{0,0,0,0}, aI{0,0,0,0}, aH{0,0,0,0};
#pragma unroll
      for (int ks = 0; ks < 9; ++ks) {
        aR = mfma(a9[ks], wR1[ks], aR);
        aZ = mfma(a9[ks], wZ1[ks], aZ);
        if (ks < 2) aI = mfma(a9[ks], wI1[ks], aI);
        else        aH = mfma(a9[ks], wH1[ks-2], aH);
      }
#pragma unroll
      for (int i = 0; i < 4; ++i) {
        int m = kg*4 + i;
        float r = sigm(aR[i] + bR1);
        float z = sigm(aZ[i] + bZ1);
        float n = tanhf_(aI[i] + bI1 + r*(aH[i] + bH1));
        float hold = b2f(ld27(hO, m, cj));
        float hnew = (1.f - z)*n + z*hold;
        st27(hN, m, cj, f2b(hnew));
        out[(size_t)(m0+m)*LL*OUTC + outB + 150 + cj] = hnew;
      }
    } else {
      f32x4 aR1{0,0,0,0}, aZ1{0,0,0,0}, aI1{0,0,0,0}, aH1{0,0,0,0};
      f32x4 aR2{0,0,0,0}, aZ2{0,0,0,0}, aI2{0,0,0,0}, aH2{0,0,0,0};
#pragma unroll
      for (int ks = 0; ks < 9; ++ks) {
        aR1 = mfma(a9[ks], wR1[ks], aR1); aR2 = mfma(a9[ks], wR2[ks], aR2);
        aZ1 = mfma(a9[ks], wZ1[ks], aZ1); aZ2 = mfma(a9[ks], wZ2[ks], aZ2);
        if (ks < 2) {
          aI1 = mfma(a9[ks], wI1[ks], aI1); aI2 = mfma(a9[ks], wI2[ks], aI2);
        } else {
          aH1 = mfma(a9[ks], wH1[ks-2], aH1); aH2 = mfma(a9[ks], wH2[ks-2], aH2);
        }
      }
#pragma unroll
      for (int i = 0; i < 4; ++i) {
        int m = kg*4 + i;
        float r = sigm(aR1[i] + bR1);
        float z = sigm(aZ1[i] + bZ1);
        float n = tanhf_(aI1[i] + bI1 + r*(aH1[i] + bH1));
        float hold = b2f(ld27(hO, m, cj));
        float hnew = (1.f - z)*n + z*hold;
        st27(hN, m, cj, f2b(hnew));
        out[(size_t)(m0+m)*LL*OUTC + outB + 150 + cj] = hnew;
      }
      if (cj2 < 200) {
#pragma unroll
        for (int i = 0; i < 4; ++i) {
          int m = kg*4 + i;
          float r = sigm(aR2[i] + bR2);
          float z = sigm(aZ2[i] + bZ2);
          float n = tanhf_(aI2[i] + bI2 + r*(aH2[i] + bH2));
          float hold = b2f(ld27(hO, m, cj2));
          float hnew = (1.f - z)*n + z*hold;
          st27(hN, m, cj2, f2b(hnew));
          out[(size_t)(m0+m)*LL*OUTC + outB + 150 + cj2] = hnew;
        }
      }
    }
    __syncthreads();

    // ================= P2: q1h GEMM (LDS weights) ===========================
    {
      short8 g[7];
#pragma unroll
      for (int ks = 0; ks < 7; ++ks) g[ks] = ldA7(hN, nl, ks*32 + kg*8);
      f32x4 aq1{0,0,0,0}, aq2{0,0,0,0};
#pragma unroll
      for (int ks = 0; ks < 7; ++ks) {
        aq1 = mfma(g[ks], lwq(swq, w*7 + ks, lane), aq1);
        if (j2) aq2 = mfma(g[ks], lwq(swq, tq2*7 + ks, lane), aq2);
      }
#pragma unroll
      for (int i = 0; i < 4; ++i) {
        int m = kg*4 + i;
        float v = aq1[i] + qx1[i];
        st23(sqq, m, cj, f2b(v > 0.f ? v : 0.f));
      }
      if (cj2v) {
#pragma unroll
        for (int i = 0; i < 4; ++i) {
          int m = kg*4 + i;
          float v = aq2[i] + qx2[i];
          st23(sqq, m, cj2, f2b(v > 0.f ? v : 0.f));
        }
      }
    }
    __syncthreads();

    // ================= P3: q2 heads + reparam (waves 0,1; LDS weights) ======
    if (isP3) {
      f32x4 a0{0,0,0,0}, a1{0,0,0,0};
#pragma unroll
      for (int ks = 0; ks < 7; ++ks) {
        short8 af = ldA3(sqq, nl, ks*32 + kg*8);
        a0 = mfma(af, lwq(swq, 91 + w*7 + ks,     lane), a0);
        a1 = mfma(af, lwq(swq, 91 + (w+2)*7 + ks, lane), a1);
      }
      if (c3 < 30) {
#pragma unroll
        for (int i = 0; i < 4; ++i) {
          int m = kg*4 + i;
          size_t ob = (size_t)(m0+m)*LL*OUTC + outB;
          float mu = a0[i] + b3mu;
          float sp = softplus_(a1[i] + b3pre) + 1e-5f;
          float sd = fmaxf(sp, 1e-4f);
          float s = mu + sd*ep[i];
          out[ob +  60 + c3] = mu;
          out[ob +  90 + c3] = sd;
          out[ob + 120 + c3] = s;
          st27(hN, m, 200 + c3, f2b(s));
        }
      }
    } else if (isAct && (l + 1 < LL)) {
      st27(hN, t2/6, 230 + (t2 % 6), f2b(av));
    }
    __syncthreads();
  }
}

extern "C" void kernel_launch(void* const* d_in, const int* in_sizes, int n_in,
                              void* d_out, int out_size, void* d_ws, size_t ws_size,
                              hipStream_t stream) {
  const float* obs   = (const float*)d_in[0];
  const float* act   = (const float*)d_in[1];
  const float* noise = (const float*)d_in[2];
  const float* W_ih  = (const float*)d_in[3];
  const float* b_ih  = (const float*)d_in[4];
  const float* W_hh  = (const float*)d_in[5];
  const float* b_hh  = (const float*)d_in[6];
  const float* pW1   = (const float*)d_in[7];
  const float* pb1   = (const float*)d_in[8];
  const float* pW2   = (const float*)d_in[9];
  const float* pb2   = (const float*)d_in[10];
  const float* qW1   = (const float*)d_in[11];
  const float* qb1   = (const float*)d_in[12];
  const float* qW2   = (const float*)d_in[13];
  const float* qb2   = (const float*)d_in[14];
  float* out = (float*)d_out;
  u16* qxp = (u16*)((char*)d_ws + QX_OFF);

  pack_w<<<U_TOT, 512, 0, stream>>>(W_ih, W_hh, pW1, qW1, pW2, qW2, (u16*)d_ws);
  qx_k<<<8192, 512, 0, stream>>>(obs, qb1, (const char*)d_ws, qxp);
  rssm_seq<<<128, 512, 0, stream>>>(act, noise, b_ih, b_hh, qb2,
                                    qxp, (const char*)d_ws, out);
  prior_k<<<8192, 512, 0, stream>>>(pb1, pb2, (const char*)d_ws, out);
}

// Round 7
// 732.982 us; speedup vs baseline: 1.1142x; 1.1142x over previous
//
#include <hip/hip_runtime.h>

// RSSM v7: pack_w + qx_k + prior_k unchanged (verified r4/r5).
// rssm_seq restructured (v5 base, register-persistence abandoned after r2/r6):
//   Phase A: gh = h(l-1)@W_hh (21 units/job, the big L2 stream) in parallel
//            with q2(l-1)+reparam on waves 0-1 (partial gate sums in 24 regs)
//   Phase B: gi = x@W_ih (6 units) + gate combine + h update
//   Phase C: q1h (LDS weights) + qx add + act staging
// Raw barriers (lgkmcnt(0)+s_barrier) so out[] HBM stores / global loads are
// NOT drained at phase boundaries (vs __syncthreads' vmcnt(0)).

typedef unsigned short u16;
typedef unsigned int u32;
typedef __attribute__((ext_vector_type(8))) short short8;
typedef __attribute__((ext_vector_type(4))) float f32x4;

#define LL 64
#define OBS_ 200
#define ACT_ 6
#define STO 30
#define OUTC 350

// packed-weight unit offsets (1 unit = 1KB = 64 lanes x 16B)
#define U_WG   0
#define U_PW1  468
#define U_QW1  559
#define U_PW2  741
#define U_QW2  769
#define U_TOT  797
#define QX_OFF (1u << 20)

// raw phase barrier: order LDS ops only; leave global stores/loads in flight
#define BAR() do { \
  asm volatile("s_waitcnt lgkmcnt(0)" ::: "memory"); \
  __builtin_amdgcn_s_barrier(); \
  __builtin_amdgcn_sched_barrier(0); \
} while (0)

__device__ __forceinline__ u16 f2b(float f){
  u32 u = __float_as_uint(f);
  u = (u + 0x7fffu + ((u >> 16) & 1u)) >> 16;   // RNE
  return (u16)u;
}
__device__ __forceinline__ float b2f(u16 h){ return __uint_as_float(((u32)h) << 16); }

// stride-512B tiles (h): swizzle byte ^= (r&7)<<4
__device__ __forceinline__ short8 ldA7(const u16* buf, int r, int colStart){
  return *(const short8*)((const char*)buf + r*512 + ((colStart*2) ^ ((r & 7) << 4)));
}
__device__ __forceinline__ void st27(u16* buf, int r, int c, u16 v){
  *(u16*)((char*)buf + r*512 + ((c*2) ^ ((r & 7) << 4))) = v;
}
__device__ __forceinline__ u16 ld27(const u16* buf, int r, int c){
  return *(const u16*)((const char*)buf + r*512 + ((c*2) ^ ((r & 7) << 4)));
}
// stride-448B tiles (sqq/sob/shh/spp): swizzle byte ^= (r&3)<<4
__device__ __forceinline__ short8 ldA3(const u16* buf, int r, int colStart){
  return *(const short8*)((const char*)buf + r*448 + ((colStart*2) ^ ((r & 3) << 4)));
}
__device__ __forceinline__ void st23(u16* buf, int r, int c, u16 v){
  *(u16*)((char*)buf + r*448 + ((c*2) ^ ((r & 3) << 4))) = v;
}
__device__ __forceinline__ void st8_3(u16* buf, int r, int c8, short8 v){
  *(short8*)((char*)buf + r*448 + ((c8*16) ^ ((r & 3) << 4))) = v;
}
__device__ __forceinline__ short8 ldB(const char* wsb, int unit, int lane){
  return *(const short8*)(wsb + (((size_t)unit) << 10) + ((size_t)lane << 4));
}
__device__ __forceinline__ short8 lwq(const u16* sw, int lu, int lane){
  return *(const short8*)((const char*)sw + ((size_t)lu << 10) + (lane << 4));
}
__device__ __forceinline__ f32x4 mfma(short8 a, short8 b, f32x4 c){
  return __builtin_amdgcn_mfma_f32_16x16x32_bf16(a, b, c, 0, 0, 0);
}
__device__ __forceinline__ float sigm(float x){ return 1.f / (1.f + __expf(-x)); }
__device__ __forceinline__ float tanhf_(float x){
  x = fminf(fmaxf(x, -15.f), 15.f);
  float e = __expf(-2.f * x);
  return (1.f - e) / (1.f + e);
}
__device__ __forceinline__ float softplus_(float x){
  return (x > 20.f) ? x : log1pf(__expf(x));
}
__device__ __forceinline__ short8 pack8(f32x4 a, f32x4 b){
  short8 v;
  v[0]=(short)f2b(a[0]); v[1]=(short)f2b(a[1]); v[2]=(short)f2b(a[2]); v[3]=(short)f2b(a[3]);
  v[4]=(short)f2b(b[0]); v[5]=(short)f2b(b[1]); v[6]=(short)f2b(b[2]); v[7]=(short)f2b(b[3]);
  return v;
}

// ---------------- weight packing (UNCHANGED, verified round 1) ---------------
__global__ __launch_bounds__(512) void pack_w(
    const float* W_ih, const float* W_hh, const float* pW1f, const float* qW1f,
    const float* pW2f, const float* qW2f, u16* wsu)
{
  int u = blockIdx.x;
  int t = threadIdx.x;
  int lane = t >> 3, j = t & 7;
  int nl = lane & 15, kg = lane >> 4;
  float v = 0.f;
  if (u < U_PW1) {                       // WG
    int nt = u / 9, ks = u % 9;
    int k = ks*32 + kg*8 + j;
    int c = nt*16 + nl;
    int grow, part, coff;
    if (c < 208)      { grow = c;            part = 0; coff = c; }
    else if (c < 416) { grow = 200 + (c-208); part = 0; coff = c-208; }
    else if (c < 624) { grow = 400 + (c-416); part = 1; coff = c-416; }
    else              { grow = 400 + (c-624); part = 2; coff = c-624; }
    if (coff < 200) {
      if (k < 36)                  { if (part != 2) v = W_ih[grow*36 + k]; }
      else if (k >= 64 && k < 264) { if (part != 1) v = W_hh[grow*200 + (k-64)]; }
    }
  } else if (u < U_QW1) {                // PW1
    int uu = u - U_PW1; int nt = uu / 7, ks = uu % 7;
    int k = ks*32 + kg*8 + j; int n = nt*16 + nl;
    if (n < 200 && k < 200) v = pW1f[n*200 + k];
  } else if (u < U_PW2) {                // QW1
    int uu = u - U_QW1; int nt = uu / 14, ks = uu % 14;
    int k = ks*32 + kg*8 + j; int n = nt*16 + nl;
    if (n < 200) {
      if (k < 200) v = qW1f[n*400 + k];
      else if (k >= 224 && k < 424) v = qW1f[n*400 + 200 + (k-224)];
    }
  } else {                               // PW2 / QW2
    bool isQ = (u >= U_QW2);
    int uu = u - (isQ ? U_QW2 : U_PW2); int nt = uu / 7, ks = uu % 7;
    int k = ks*32 + kg*8 + j; int c = nt*16 + nl;
    int row = (c < 32) ? c : 30 + (c - 32);
    bool ok = (c < 32) ? (c < 30) : ((c - 32) < 30);
    const float* W = isQ ? qW2f : pW2f;
    if (ok && k < 200) v = W[row*200 + k];
  }
  wsu[((size_t)u << 9) + lane*8 + j] = f2b(v);
}

// ---------------- qx kernel (UNCHANGED, verified round 4) --------------------
__global__ __launch_bounds__(512) void qx_k(
    const float* __restrict__ obs, const float* __restrict__ qb1,
    const char* __restrict__ wsb, u16* __restrict__ qxp)
{
  const int tid = threadIdx.x, w = tid >> 6, lane = tid & 63;
  const int nl = lane & 15, kg = lane >> 4;
  const int r0 = blockIdx.x * 16;
  __shared__ __align__(16) u16 sob[16*224];
  for (int i = tid; i < 16*224; i += 512) sob[i] = 0;
  __syncthreads();
  if (tid < 400) {
    int m = tid / 25, c8 = tid % 25;
    const float* op = obs + (size_t)(r0+m)*OBS_ + c8*8;
    f32x4 a = *(const f32x4*)op, b = *(const f32x4*)(op + 4);
    st8_3(sob, m, c8, pack8(a, b));
  }
  __syncthreads();
#pragma unroll
  for (int qi = 0; qi < 2; ++qi) {
    int tq = w + qi*8;
    if (tq < 13) {
      f32x4 acc{0,0,0,0};
#pragma unroll
      for (int ks = 0; ks < 7; ++ks)
        acc = mfma(ldA3(sob, nl, ks*32 + kg*8), ldB(wsb, U_QW1 + tq*14 + ks, lane), acc);
      int n = tq*16 + nl;
      if (n < 200) {
        float b = qb1[n];
#pragma unroll
        for (int i = 0; i < 4; ++i)
          qxp[(size_t)(r0 + kg*4 + i)*OBS_ + n] = f2b(acc[i] + b);
      }
    }
  }
}

// ---------------- prior kernel (UNCHANGED, verified round 4) -----------------
__global__ __launch_bounds__(512) void prior_k(
    const float* __restrict__ pb1, const float* __restrict__ pb2,
    const char* __restrict__ wsb, float* __restrict__ out)
{
  const int tid = threadIdx.x, w = tid >> 6, lane = tid & 63;
  const int nl = lane & 15, kg = lane >> 4;
  const int r0 = blockIdx.x * 16;
  __shared__ __align__(16) u16 shh[16*224];
  __shared__ __align__(16) u16 spp[16*224];
  for (int i = tid; i < 16*224; i += 512) { shh[i] = 0; spp[i] = 0; }
  __syncthreads();
  if (tid < 400) {
    int m = tid / 25, c8 = tid % 25;
    const float* hp = out + (size_t)(r0+m)*OUTC + 150 + c8*8;
    f32x4 a, b;
#pragma unroll
    for (int i = 0; i < 4; ++i) { a[i] = hp[i]; b[i] = hp[4+i]; }
    st8_3(shh, m, c8, pack8(a, b));
  }
  __syncthreads();
#pragma unroll
  for (int qi = 0; qi < 2; ++qi) {
    int tq = w + qi*8;
    if (tq < 13) {
      f32x4 acc{0,0,0,0};
#pragma unroll
      for (int ks = 0; ks < 7; ++ks)
        acc = mfma(ldA3(shh, nl, ks*32 + kg*8), ldB(wsb, U_PW1 + tq*7 + ks, lane), acc);
      int n = tq*16 + nl;
      if (n < 200) {
        float b = pb1[n];
#pragma unroll
        for (int i = 0; i < 4; ++i) {
          float v = acc[i] + b;
          st23(spp, kg*4 + i, n, f2b(v > 0.f ? v : 0.f));
        }
      }
    }
  }
  __syncthreads();
  if (w < 2) {
    f32x4 a0{0,0,0,0}, a1{0,0,0,0};
#pragma unroll
    for (int ks = 0; ks < 7; ++ks) {
      short8 af = ldA3(spp, nl, ks*32 + kg*8);
      a0 = mfma(af, ldB(wsb, U_PW2 + w*7 + ks,     lane), a0);
      a1 = mfma(af, ldB(wsb, U_PW2 + (w+2)*7 + ks, lane), a1);
    }
    int c3 = w*16 + nl;
    if (c3 < 30) {
      float bmu = pb2[c3], bpre = pb2[30 + c3];
#pragma unroll
      for (int i = 0; i < 4; ++i) {
        size_t ob = (size_t)(r0 + kg*4 + i)*OUTC;
        out[ob + c3] = a0[i] + bmu;
        float sp = softplus_(a1[i] + bpre) + 1e-5f;
        out[ob + 30 + c3] = fmaxf(sp, 1e-4f);
      }
    }
  }
}

// ---------------- sequential scan v7: split-gate pipeline --------------------
__global__ __launch_bounds__(512, 2) void rssm_seq(
    const float* __restrict__ act, const float* __restrict__ noise,
    const float* __restrict__ b_ih, const float* __restrict__ b_hh,
    const float* __restrict__ qb2,
    const u16* __restrict__ qxp, const char* __restrict__ wsb,
    float* __restrict__ out)
{
  const int tid  = threadIdx.x;
  const int w    = tid >> 6;      // wave 0..7
  const int lane = tid & 63;
  const int nl   = lane & 15;
  const int kg   = lane >> 4;
  const int m0   = blockIdx.x * 16;

  // LDS weight cache: 119 units = QW1h (tq*7+ks, 91) then QW2 (nt*7+ks, 28)
  __shared__ __align__(16) u16 swq[119*512];
  // h0/h1: [16][256] stride 512B: h 0..199 | s 200..229 | a 230..235 | zeros
  __shared__ __align__(16) u16 h0 [16*256];
  __shared__ __align__(16) u16 h1 [16*256];
  __shared__ __align__(16) u16 sqq[16*224];   // stride 448B

  for (int i = tid; i < 16*256; i += 512) { h0[i]=0; h1[i]=0; }
  for (int i = tid; i < 16*224; i += 512) sqq[i]=0;
  // load LDS weight cache (one-time, 119KB)
  for (int c = tid; c < 119*64; c += 512) {
    int lu = c >> 6, l16 = c & 63;
    int gu = (lu < 91) ? (U_QW1 + (lu/7)*14 + 7 + (lu%7)) : (U_QW2 + (lu - 91));
    *(short8*)((char*)swq + (size_t)c*16) =
        *(const short8*)(wsb + ((size_t)gu << 10) + (l16 << 4));
  }

  // ---- roles ----
  // job1: tq = w (all 8 waves). job2 (waves 3..7): tq2 = w+5 (8..12).
  const int  cj  = w*16 + nl;                       // < 128, always valid
  const bool j2  = (w >= 3);
  const int  tq2 = w + 5;
  const int  cj2 = tq2*16 + nl;
  const bool cj2v = j2 && (cj2 < 200);
  const float bR1 = b_ih[cj]       + b_hh[cj];
  const float bZ1 = b_ih[200 + cj] + b_hh[200 + cj];
  const float bI1 = b_ih[400 + cj];
  const float bH1 = b_hh[400 + cj];
  float bR2=0,bZ2=0,bI2=0,bH2=0;
  if (cj2v) {
    bR2 = b_ih[cj2] + b_hh[cj2];
    bZ2 = b_ih[200+cj2] + b_hh[200+cj2];
    bI2 = b_ih[400+cj2];
    bH2 = b_hh[400+cj2];
  }
  // q2 role (in Phase A): waves 0,1 (mu tile w, pre tile w+2 of QW2)
  const bool isP3 = (w < 2);
  const int  c3   = w*16 + nl;
  const bool c3v  = isP3 && (c3 < 30);
  float b3mu=0, b3pre=0;
  if (c3v) { b3mu = qb2[c3]; b3pre = qb2[30 + c3]; }
  // act stagers: waves 2,3 (96 lanes), store in Phase C
  const int  t2 = (w - 2)*64 + lane;
  const bool isAct = (w == 2 || w == 3) && (t2 < 96);

  __syncthreads();
  // prologue: act(l=0) -> h0 cols 230..235 (s0=h0=0 already)
  if (tid < 96) {
    int m = tid / 6, j = tid % 6;
    st27(h0, m, 230 + j, f2b(act[(size_t)(m0+m)*LL*ACT_ + j]));
  }
  __syncthreads();

#pragma unroll 1
  for (int l = 0; l < LL; ++l) {
    u16* hO = (l & 1) ? h1 : h0;
    u16* hN = (l & 1) ? h0 : h1;

    // ---- loop-top prefetches (overlap Phase A's weight stream) ----
    float ep[4] = {0,0,0,0};            // eps for q2 of step l-1
    if (c3v && l > 0) {
      const float* np = noise + (size_t)(m0 + kg*4)*LL*STO + (size_t)(l-1)*STO + c3;
#pragma unroll
      for (int i = 0; i < 4; ++i) ep[i] = np[(size_t)i*LL*STO];
    }
    float qx1[4], qx2[4] = {0,0,0,0};   // qx(l), used in Phase C
#pragma unroll
    for (int i = 0; i < 4; ++i)
      qx1[i] = b2f(qxp[((size_t)(m0 + kg*4 + i)*LL + l)*OBS_ + cj]);
    if (cj2v) {
#pragma unroll
      for (int i = 0; i < 4; ++i)
        qx2[i] = b2f(qxp[((size_t)(m0 + kg*4 + i)*LL + l)*OBS_ + cj2]);
    }
    float av = 0.f;                     // act(l+1), stored in Phase C
    if (isAct && (l + 1 < LL))
      av = act[((size_t)(m0 + t2/6)*LL + (l+1))*ACT_ + (t2 % 6)];

    // ================= Phase A: gh = h(l-1) @ W_hh  ||  q2(l-1) =============
    short8 a7[7];
#pragma unroll
    for (int j = 0; j < 7; ++j) a7[j] = ldA7(hO, nl, j*32 + kg*8);

    f32x4 hr1{0,0,0,0}, hz1{0,0,0,0}, hn1{0,0,0,0};
    f32x4 hr2{0,0,0,0}, hz2{0,0,0,0}, hn2{0,0,0,0};
#pragma unroll
    for (int j = 0; j < 7; ++j) {
      hr1 = mfma(a7[j], ldB(wsb, U_WG + w*9 + 2 + j,      lane), hr1);
      hz1 = mfma(a7[j], ldB(wsb, U_WG + (13+w)*9 + 2 + j, lane), hz1);
      hn1 = mfma(a7[j], ldB(wsb, U_WG + (39+w)*9 + 2 + j, lane), hn1);
      if (j2) {
        hr2 = mfma(a7[j], ldB(wsb, U_WG + tq2*9 + 2 + j,      lane), hr2);
        hz2 = mfma(a7[j], ldB(wsb, U_WG + (13+tq2)*9 + 2 + j, lane), hz2);
        hn2 = mfma(a7[j], ldB(wsb, U_WG + (39+tq2)*9 + 2 + j, lane), hn2);
      }
    }
    if (isP3 && l > 0) {                // q2(l-1) + reparam, concurrent
      f32x4 q0{0,0,0,0}, q1a{0,0,0,0};
#pragma unroll
      for (int ks = 0; ks < 7; ++ks) {
        short8 af = ldA3(sqq, nl, ks*32 + kg*8);
        q0  = mfma(af, lwq(swq, 91 + w*7 + ks,     lane), q0);
        q1a = mfma(af, lwq(swq, 91 + (w+2)*7 + ks, lane), q1a);
      }
      if (c3 < 30) {
#pragma unroll
        for (int i = 0; i < 4; ++i) {
          int m = kg*4 + i;
          size_t ob = (size_t)(m0+m)*LL*OUTC + (size_t)(l-1)*OUTC;
          float mu = q0[i] + b3mu;
          float sp = softplus_(q1a[i] + b3pre) + 1e-5f;
          float sd = fmaxf(sp, 1e-4f);
          float s = mu + sd*ep[i];
          out[ob +  60 + c3] = mu;
          out[ob +  90 + c3] = sd;
          out[ob + 120 + c3] = s;
          st27(hO, m, 200 + c3, f2b(s));   // s(l-1) -> x-slot for Phase B
        }
      }
    }
    BAR();

    // ================= Phase B: gi = x @ W_ih + combine + h update ==========
    {
      short8 x0 = ldA7(hO, nl, 200 + kg*8);
      short8 x1 = ldA7(hO, nl, 232 + kg*8);
      f32x4 aI1{0,0,0,0}, aI2{0,0,0,0};
      hr1 = mfma(x0, ldB(wsb, U_WG + w*9 + 0,      lane), hr1);
      hr1 = mfma(x1, ldB(wsb, U_WG + w*9 + 1,      lane), hr1);
      hz1 = mfma(x0, ldB(wsb, U_WG + (13+w)*9 + 0, lane), hz1);
      hz1 = mfma(x1, ldB(wsb, U_WG + (13+w)*9 + 1, lane), hz1);
      aI1 = mfma(x0, ldB(wsb, U_WG + (26+w)*9 + 0, lane), aI1);
      aI1 = mfma(x1, ldB(wsb, U_WG + (26+w)*9 + 1, lane), aI1);
      if (j2) {
        hr2 = mfma(x0, ldB(wsb, U_WG + tq2*9 + 0,      lane), hr2);
        hr2 = mfma(x1, ldB(wsb, U_WG + tq2*9 + 1,      lane), hr2);
        hz2 = mfma(x0, ldB(wsb, U_WG + (13+tq2)*9 + 0, lane), hz2);
        hz2 = mfma(x1, ldB(wsb, U_WG + (13+tq2)*9 + 1, lane), hz2);
        aI2 = mfma(x0, ldB(wsb, U_WG + (26+tq2)*9 + 0, lane), aI2);
        aI2 = mfma(x1, ldB(wsb, U_WG + (26+tq2)*9 + 1, lane), aI2);
      }
#pragma unroll
      for (int i = 0; i < 4; ++i) {
        int m = kg*4 + i;
        float r = sigm(hr1[i] + bR1);
        float z = sigm(hz1[i] + bZ1);
        float n = tanhf_(aI1[i] + bI1 + r*(hn1[i] + bH1));
        float hold = b2f(ld27(hO, m, cj));
        float hnew = (1.f - z)*n + z*hold;
        st27(hN, m, cj, f2b(hnew));
        out[(size_t)(m0+m)*LL*OUTC + (size_t)l*OUTC + 150 + cj] = hnew;
      }
      if (cj2v) {
#pragma unroll
        for (int i = 0; i < 4; ++i) {
          int m = kg*4 + i;
          float r = sigm(hr2[i] + bR2);
          float z = sigm(hz2[i] + bZ2);
          float n = tanhf_(aI2[i] + bI2 + r*(hn2[i] + bH2));
          float hold = b2f(ld27(hO, m, cj2));
          float hnew = (1.f - z)*n + z*hold;
          st27(hN, m, cj2, f2b(hnew));
          out[(size_t)(m0+m)*LL*OUTC + (size_t)l*OUTC + 150 + cj2] = hnew;
        }
      }
    }
    BAR();

    // ================= Phase C: q1h (LDS weights) + qx + act stage ==========
    {
      short8 g[7];
#pragma unroll
      for (int ks = 0; ks < 7; ++ks) g[ks] = ldA7(hN, nl, ks*32 + kg*8);
      f32x4 aq1{0,0,0,0}, aq2{0,0,0,0};
#pragma unroll
      for (int ks = 0; ks < 7; ++ks) {
        aq1 = mfma(g[ks], lwq(swq, w*7 + ks, lane), aq1);
        if (j2) aq2 = mfma(g[ks], lwq(swq, tq2*7 + ks, lane), aq2);
      }
#pragma unroll
      for (int i = 0; i < 4; ++i) {
        int m = kg*4 + i;
        float v = aq1[i] + qx1[i];
        st23(sqq, m, cj, f2b(v > 0.f ? v : 0.f));
      }
      if (cj2v) {
#pragma unroll
        for (int i = 0; i < 4; ++i) {
          int m = kg*4 + i;
          float v = aq2[i] + qx2[i];
          st23(sqq, m, cj2, f2b(v > 0.f ? v : 0.f));
        }
      }
      if (isAct && (l + 1 < LL))
        st27(hN, t2/6, 230 + (t2 % 6), f2b(av));
    }
    BAR();
  }

  // ---- epilogue: q2(63) + reparam ----
  if (isP3) {
    float ep[4] = {0,0,0,0};
    if (c3v) {
      const float* np = noise + (size_t)(m0 + kg*4)*LL*STO + (size_t)(LL-1)*STO + c3;
#pragma unroll
      for (int i = 0; i < 4; ++i) ep[i] = np[(size_t)i*LL*STO];
    }
    f32x4 q0{0,0,0,0}, q1a{0,0,0,0};
#pragma unroll
    for (int ks = 0; ks < 7; ++ks) {
      short8 af = ldA3(sqq, nl, ks*32 + kg*8);
      q0  = mfma(af, lwq(swq, 91 + w*7 + ks,     lane), q0);
      q1a = mfma(af, lwq(swq, 91 + (w+2)*7 + ks, lane), q1a);
    }
    if (c3 < 30) {
#pragma unroll
      for (int i = 0; i < 4; ++i) {
        int m = kg*4 + i;
        size_t ob = (size_t)(m0+m)*LL*OUTC + (size_t)(LL-1)*OUTC;
        float mu = q0[i] + b3mu;
        float sp = softplus_(q1a[i] + b3pre) + 1e-5f;
        float sd = fmaxf(sp, 1e-4f);
        out[ob +  60 + c3] = mu;
        out[ob +  90 + c3] = sd;
        out[ob + 120 + c3] = mu + sd*ep[i];
      }
    }
  }
}

extern "C" void kernel_launch(void* const* d_in, const int* in_sizes, int n_in,
                              void* d_out, int out_size, void* d_ws, size_t ws_size,
                              hipStream_t stream) {
  const float* obs   = (const float*)d_in[0];
  const float* act   = (const float*)d_in[1];
  const float* noise = (const float*)d_in[2];
  const float* W_ih  = (const float*)d_in[3];
  const float* b_ih  = (const float*)d_in[4];
  const float* W_hh  = (const float*)d_in[5];
  const float* b_hh  = (const float*)d_in[6];
  const float* pW1   = (const float*)d_in[7];
  const float* pb1   = (const float*)d_in[8];
  const float* pW2   = (const float*)d_in[9];
  const float* pb2   = (const float*)d_in[10];
  const float* qW1   = (const float*)d_in[11];
  const float* qb1   = (const float*)d_in[12];
  const float* qW2   = (const float*)d_in[13];
  const float* qb2   = (const float*)d_in[14];
  float* out = (float*)d_out;
  u16* qxp = (u16*)((char*)d_ws + QX_OFF);

  pack_w<<<U_TOT, 512, 0, stream>>>(W_ih, W_hh, pW1, qW1, pW2, qW2, (u16*)d_ws);
  qx_k<<<8192, 512, 0, stream>>>(obs, qb1, (const char*)d_ws, qxp);
  rssm_seq<<<128, 512, 0, stream>>>(act, noise, b_ih, b_hh, qb2,
                                    qxp, (const char*)d_ws, out);
  prior_k<<<8192, 512, 0, stream>>>(pb1, pb2, (const char*)d_ws, out);
}